// Round 1
// baseline (2527.130 us; speedup 1.0000x reference)
//
#include <hip/hip_runtime.h>
#include <hip/hip_cooperative_groups.h>
#include <cstdint>

namespace cg = cooperative_groups;

#define T_STEPS 128
#define BATCH 64
#define IDIM 2048
#define HDIM 512
#define G4 2048   // 4*H
#define NCLS 11

typedef __attribute__((ext_vector_type(8))) short bf16x8;
typedef __attribute__((ext_vector_type(4))) float f32x4;

__device__ __forceinline__ unsigned short f2bf(float f) {
    unsigned int u = __builtin_bit_cast(unsigned int, f);
    unsigned int r = u + 0x7FFFu + ((u >> 16) & 1u);   // RNE
    return (unsigned short)(r >> 16);
}
__device__ __forceinline__ float bf2f(unsigned short b) {
    unsigned int u = ((unsigned int)b) << 16;
    return __builtin_bit_cast(float, u);
}

// ---------------------------------------------------------------------------
// Prep: permute gate rows to interleaved order (n' = 4*j + gate), split
// weights into bf16 hi/lo, combine biases, split h0 into h buffer 0.
// orig_row(n') = (n'&3)*512 + (n'>>2)
// ---------------------------------------------------------------------------
__global__ void prep_kernel(const float* __restrict__ W_ih, const float* __restrict__ W_hh,
                            const float* __restrict__ b_ih, const float* __restrict__ b_hh,
                            const float* __restrict__ h0,
                            unsigned short* __restrict__ wih_hi, unsigned short* __restrict__ wih_lo,
                            unsigned short* __restrict__ whh_hi, unsigned short* __restrict__ whh_lo,
                            float* __restrict__ bc,
                            unsigned short* __restrict__ h_hi, unsigned short* __restrict__ h_lo) {
    int idx = blockIdx.x * blockDim.x + threadIdx.x;
    int stride = gridDim.x * blockDim.x;
    for (int i = idx; i < G4 * IDIM; i += stride) {
        int np = i / IDIM, k = i - np * IDIM;
        int orig = (np & 3) * HDIM + (np >> 2);
        float f = W_ih[(size_t)orig * IDIM + k];
        unsigned short hi = f2bf(f);
        wih_hi[i] = hi;
        wih_lo[i] = f2bf(f - bf2f(hi));
    }
    for (int i = idx; i < G4 * HDIM; i += stride) {
        int np = i / HDIM, k = i - np * HDIM;
        int orig = (np & 3) * HDIM + (np >> 2);
        float f = W_hh[(size_t)orig * HDIM + k];
        unsigned short hi = f2bf(f);
        whh_hi[i] = hi;
        whh_lo[i] = f2bf(f - bf2f(hi));
    }
    for (int i = idx; i < G4; i += stride) {
        int orig = (i & 3) * HDIM + (i >> 2);
        bc[i] = b_ih[orig] + b_hh[orig];
    }
    for (int i = idx; i < BATCH * HDIM; i += stride) {
        float f = h0[i];
        unsigned short hi = f2bf(f);
        h_hi[i] = hi;                       // buffer 0
        h_lo[i] = f2bf(f - bf2f(hi));
    }
}

// ---------------------------------------------------------------------------
// xg GEMM: xg[8192][2048] = x[8192][2048] @ Wih''^T + bc   (split-3 bf16 MFMA)
// 128x128 tile, BK=64, 256 threads (4 waves, each a 64x64 quadrant).
// ---------------------------------------------------------------------------
__global__ __launch_bounds__(256) void gemm_xg(const float* __restrict__ x,
        const unsigned short* __restrict__ wih_hi, const unsigned short* __restrict__ wih_lo,
        const float* __restrict__ bc, float* __restrict__ xg) {
    __shared__ unsigned short As_hi[128][64];
    __shared__ unsigned short As_lo[128][64];
    __shared__ unsigned short Bs_hi[128][64];
    __shared__ unsigned short Bs_lo[128][64];

    int tid = threadIdx.x;
    int w = tid >> 6, l = tid & 63;
    int lr = l & 15, lc = l >> 4;
    int bid = blockIdx.x;
    int mt = bid & 63, nt = bid >> 6;       // 64 M-tiles x 16 N-tiles
    int m0 = mt * 128, n0 = nt * 128;
    int mq = (w >> 1) * 64, nq = (w & 1) * 64;

    f32x4 acc[4][4] = {};

    for (int k0 = 0; k0 < IDIM; k0 += 64) {
        // stage A: f32 -> bf16 hi/lo
        #pragma unroll
        for (int i = 0; i < 8; ++i) {
            int p = i * 256 + tid;            // 0..2047 : 128 rows x 16 chunks
            int r = p >> 4, c4 = p & 15;
            const float4 v = *(const float4*)(x + (size_t)(m0 + r) * IDIM + k0 + c4 * 4);
            unsigned short h0_ = f2bf(v.x), h1_ = f2bf(v.y), h2_ = f2bf(v.z), h3_ = f2bf(v.w);
            unsigned short l0_ = f2bf(v.x - bf2f(h0_));
            unsigned short l1_ = f2bf(v.y - bf2f(h1_));
            unsigned short l2_ = f2bf(v.z - bf2f(h2_));
            unsigned short l3_ = f2bf(v.w - bf2f(h3_));
            uint2 hw, lw;
            hw.x = (unsigned)h0_ | ((unsigned)h1_ << 16);
            hw.y = (unsigned)h2_ | ((unsigned)h3_ << 16);
            lw.x = (unsigned)l0_ | ((unsigned)l1_ << 16);
            lw.y = (unsigned)l2_ | ((unsigned)l3_ << 16);
            *(uint2*)&As_hi[r][c4 * 4] = hw;
            *(uint2*)&As_lo[r][c4 * 4] = lw;
        }
        // stage B: bf16 copy (W'' is [n'][k], k contiguous)
        #pragma unroll
        for (int i = 0; i < 4; ++i) {
            int q = i * 256 + tid;            // 0..1023 : 128 rows x 8 chunks
            int n = q >> 3, c16 = q & 7;
            size_t goff = (size_t)(n0 + n) * IDIM + k0 + c16 * 8;
            *(uint4*)&Bs_hi[n][c16 * 8] = *(const uint4*)(wih_hi + goff);
            *(uint4*)&Bs_lo[n][c16 * 8] = *(const uint4*)(wih_lo + goff);
        }
        __syncthreads();

        #pragma unroll
        for (int ks = 0; ks < 2; ++ks) {
            bf16x8 ah[4], al[4], bh[4], bl[4];
            int col = ks * 32 + lc * 8;
            #pragma unroll
            for (int mb = 0; mb < 4; ++mb) {
                int row = mq + mb * 16 + lr;
                ah[mb] = *(const bf16x8*)&As_hi[row][col];
                al[mb] = *(const bf16x8*)&As_lo[row][col];
            }
            #pragma unroll
            for (int nb = 0; nb < 4; ++nb) {
                int row = nq + nb * 16 + lr;
                bh[nb] = *(const bf16x8*)&Bs_hi[row][col];
                bl[nb] = *(const bf16x8*)&Bs_lo[row][col];
            }
            #pragma unroll
            for (int mb = 0; mb < 4; ++mb)
                #pragma unroll
                for (int nb = 0; nb < 4; ++nb) {
                    acc[mb][nb] = __builtin_amdgcn_mfma_f32_16x16x32_bf16(ah[mb], bh[nb], acc[mb][nb], 0, 0, 0);
                    acc[mb][nb] = __builtin_amdgcn_mfma_f32_16x16x32_bf16(ah[mb], bl[nb], acc[mb][nb], 0, 0, 0);
                    acc[mb][nb] = __builtin_amdgcn_mfma_f32_16x16x32_bf16(al[mb], bh[nb], acc[mb][nb], 0, 0, 0);
                }
        }
        __syncthreads();
    }

    // epilogue: + bias, store f32
    #pragma unroll
    for (int mb = 0; mb < 4; ++mb) {
        #pragma unroll
        for (int nb = 0; nb < 4; ++nb) {
            int col = n0 + nq + nb * 16 + lr;
            float bias = bc[col];
            #pragma unroll
            for (int r = 0; r < 4; ++r) {
                int row = m0 + mq + mb * 16 + lc * 4 + r;
                xg[(size_t)row * G4 + col] = acc[mb][nb][r] + bias;
            }
        }
    }
}

// ---------------------------------------------------------------------------
// Recurrence: 64 WGs x 256 thr, cooperative. WG g owns gate cols [g*32,g*32+32)
// = hidden units j in [g*8, g*8+8). Wave w owns K-quarter [w*128,(w+1)*128).
// Whh'' fragments live in registers for all 128 steps. h double-buffered in
// global as bf16 hi/lo. One LSTM cell per thread (x2), c & sum(h) in regs.
// ---------------------------------------------------------------------------
__global__ __launch_bounds__(256) void lstm_rec(
        const unsigned short* __restrict__ whh_hi, const unsigned short* __restrict__ whh_lo,
        const float* __restrict__ xg, const float* __restrict__ c0,
        const float* __restrict__ mask_h, const float* __restrict__ mask_c,
        unsigned short* __restrict__ h_hi, unsigned short* __restrict__ h_lo,
        float* __restrict__ h_mean,
        const float* __restrict__ W_out, const float* __restrict__ b_out,
        float* __restrict__ out) {
    cg::grid_group grid = cg::this_grid();
    __shared__ float red[4][64][32];        // 32 KB: per-wave K-partials

    int g = blockIdx.x, tid = threadIdx.x;
    int w = tid >> 6, l = tid & 63;
    int lr = l & 15, lc = l >> 4;

    // B fragments (Whh'' slice), resident in registers for the whole loop
    bf16x8 bh[2][4], bl[2][4];
    #pragma unroll
    for (int nb = 0; nb < 2; ++nb)
        #pragma unroll
        for (int ks = 0; ks < 4; ++ks) {
            int n = g * 32 + nb * 16 + lr;
            int k = w * 128 + ks * 32 + lc * 8;
            bh[nb][ks] = *(const bf16x8*)(whh_hi + (size_t)n * HDIM + k);
            bl[nb][ks] = *(const bf16x8*)(whh_lo + (size_t)n * HDIM + k);
        }

    // two cells per thread
    int b0_ = tid >> 3, jl0 = tid & 7, jg0 = g * 8 + jl0;
    int b1_ = (tid + 256) >> 3, jl1 = tid & 7, jg1 = g * 8 + jl1;
    float c_0 = c0[b0_ * HDIM + jg0];
    float c_1 = c0[b1_ * HDIM + jg1];
    float ha0 = 0.f, ha1 = 0.f;

    for (int t = 0; t < T_STEPS; ++t) {
        int cur = (t & 1) * (BATCH * HDIM);
        int nxt = ((t + 1) & 1) * (BATCH * HDIM);

        f32x4 acc[4][2] = {};
        #pragma unroll
        for (int ks = 0; ks < 4; ++ks) {
            int k = w * 128 + ks * 32 + lc * 8;
            #pragma unroll
            for (int mb = 0; mb < 4; ++mb) {
                int row = mb * 16 + lr;
                bf16x8 ah = *(const bf16x8*)(h_hi + cur + row * HDIM + k);
                bf16x8 al = *(const bf16x8*)(h_lo + cur + row * HDIM + k);
                #pragma unroll
                for (int nb = 0; nb < 2; ++nb) {
                    acc[mb][nb] = __builtin_amdgcn_mfma_f32_16x16x32_bf16(ah, bh[nb][ks], acc[mb][nb], 0, 0, 0);
                    acc[mb][nb] = __builtin_amdgcn_mfma_f32_16x16x32_bf16(ah, bl[nb][ks], acc[mb][nb], 0, 0, 0);
                    acc[mb][nb] = __builtin_amdgcn_mfma_f32_16x16x32_bf16(al, bh[nb][ks], acc[mb][nb], 0, 0, 0);
                }
            }
        }
        #pragma unroll
        for (int mb = 0; mb < 4; ++mb)
            #pragma unroll
            for (int nb = 0; nb < 2; ++nb)
                #pragma unroll
                for (int r = 0; r < 4; ++r)
                    red[w][mb * 16 + lc * 4 + r][nb * 16 + lr] = acc[mb][nb][r];
        __syncthreads();

        // cell phase: 2 cells per thread
        #pragma unroll
        for (int e = 0; e < 2; ++e) {
            int b  = e ? b1_ : b0_;
            int jl = e ? jl1 : jl0;
            int jg = e ? jg1 : jg0;
            float c_reg = e ? c_1 : c_0;
            int nb4 = jl * 4;
            float gi = red[0][b][nb4 + 0] + red[1][b][nb4 + 0] + red[2][b][nb4 + 0] + red[3][b][nb4 + 0];
            float gf = red[0][b][nb4 + 1] + red[1][b][nb4 + 1] + red[2][b][nb4 + 1] + red[3][b][nb4 + 1];
            float gg = red[0][b][nb4 + 2] + red[1][b][nb4 + 2] + red[2][b][nb4 + 2] + red[3][b][nb4 + 2];
            float go = red[0][b][nb4 + 3] + red[1][b][nb4 + 3] + red[2][b][nb4 + 3] + red[3][b][nb4 + 3];
            const float* xgrow = xg + (size_t)(t * BATCH + b) * G4 + g * 32 + nb4;
            gi += xgrow[0]; gf += xgrow[1]; gg += xgrow[2]; go += xgrow[3];
            float i_s = 1.f / (1.f + expf(-gi));
            float f_s = 1.f / (1.f + expf(-gf));
            float o_s = 1.f / (1.f + expf(-go));
            float c_new = f_s * c_reg + i_s * tanhf(gg);
            float h_new = o_s * tanhf(c_new);
            size_t midx = (size_t)(t * BATCH + b) * HDIM + jg;
            h_new *= mask_h[midx];
            c_new *= mask_c[midx];
            if (e) { c_1 = c_new; ha1 += h_new; } else { c_0 = c_new; ha0 += h_new; }
            unsigned short hh = f2bf(h_new);
            unsigned short hl = f2bf(h_new - bf2f(hh));
            h_hi[nxt + b * HDIM + jg] = hh;
            h_lo[nxt + b * HDIM + jg] = hl;
        }
        grid.sync();
    }

    h_mean[b0_ * HDIM + jg0] = ha0 * (1.f / T_STEPS);
    h_mean[b1_ * HDIM + jg1] = ha1 * (1.f / T_STEPS);
    grid.sync();

    if (g == 0) {
        for (int oi = tid; oi < BATCH * NCLS; oi += 256) {
            int b = oi / NCLS, cl = oi - b * NCLS;
            float s = b_out[cl];
            for (int j = 0; j < HDIM; ++j)
                s += h_mean[b * HDIM + j] * W_out[cl * HDIM + j];
            out[oi] = s;
        }
    }
}

// ---------------------------------------------------------------------------
extern "C" void kernel_launch(void* const* d_in, const int* in_sizes, int n_in,
                              void* d_out, int out_size, void* d_ws, size_t ws_size,
                              hipStream_t stream) {
    const float* x      = (const float*)d_in[0];
    const float* h0     = (const float*)d_in[1];
    const float* c0     = (const float*)d_in[2];
    const float* W_ih   = (const float*)d_in[3];
    const float* W_hh   = (const float*)d_in[4];
    const float* b_ih   = (const float*)d_in[5];
    const float* b_hh   = (const float*)d_in[6];
    const float* W_out  = (const float*)d_in[7];
    const float* b_out  = (const float*)d_in[8];
    const float* mask_h = (const float*)d_in[9];
    const float* mask_c = (const float*)d_in[10];
    float* out = (float*)d_out;

    char* ws = (char*)d_ws;
    float*          xg     = (float*)(ws + 0);               // 67,108,864 B
    unsigned short* wih_hi = (unsigned short*)(ws + 67108864);   // 8,388,608
    unsigned short* wih_lo = (unsigned short*)(ws + 75497472);   // 8,388,608
    unsigned short* whh_hi = (unsigned short*)(ws + 83886080);   // 2,097,152
    unsigned short* whh_lo = (unsigned short*)(ws + 85983232);   // 2,097,152
    float*          bc     = (float*)(ws + 88080384);            // 8,192
    unsigned short* h_hi   = (unsigned short*)(ws + 88088576);   // 131,072 (2 bufs)
    unsigned short* h_lo   = (unsigned short*)(ws + 88219648);   // 131,072
    float*          h_mean = (float*)(ws + 88350720);            // 131,072

    prep_kernel<<<8192, 256, 0, stream>>>(W_ih, W_hh, b_ih, b_hh, h0,
                                          wih_hi, wih_lo, whh_hi, whh_lo, bc, h_hi, h_lo);
    gemm_xg<<<1024, 256, 0, stream>>>(x, wih_hi, wih_lo, bc, xg);

    void* args[] = { &whh_hi, &whh_lo, &xg, &c0, &mask_h, &mask_c,
                     &h_hi, &h_lo, &h_mean, &W_out, &b_out, &out };
    hipLaunchCooperativeKernel((void*)lstm_rec, dim3(64), dim3(256), args, 0, stream);
}

// Round 2
// 1668.537 us; speedup vs baseline: 1.5146x; 1.5146x over previous
//
#include <hip/hip_runtime.h>
#include <cstdint>

#define T_STEPS 128
#define BATCH 64
#define IDIM 2048
#define HDIM 512
#define G4 2048   // 4*H
#define NCLS 11

typedef __attribute__((ext_vector_type(8))) short bf16x8;
typedef __attribute__((ext_vector_type(4))) float f32x4;

__device__ __forceinline__ unsigned short f2bf(float f) {
    unsigned int u = __builtin_bit_cast(unsigned int, f);
    unsigned int r = u + 0x7FFFu + ((u >> 16) & 1u);   // RNE
    return (unsigned short)(r >> 16);
}
__device__ __forceinline__ float bf2f(unsigned short b) {
    unsigned int u = ((unsigned int)b) << 16;
    return __builtin_bit_cast(float, u);
}

// ---------------------------------------------------------------------------
// Prep: permute gate rows to interleaved order (n' = 4*j + gate), split
// weights into bf16 hi/lo, combine biases, split h0 into h buffer 0.
// orig_row(n') = (n'&3)*512 + (n'>>2).  Also zero the spin-barrier counter.
// ---------------------------------------------------------------------------
__global__ void prep_kernel(const float* __restrict__ W_ih, const float* __restrict__ W_hh,
                            const float* __restrict__ b_ih, const float* __restrict__ b_hh,
                            const float* __restrict__ h0,
                            unsigned short* __restrict__ wih_hi, unsigned short* __restrict__ wih_lo,
                            unsigned short* __restrict__ whh_hi, unsigned short* __restrict__ whh_lo,
                            float* __restrict__ bc,
                            unsigned short* __restrict__ h_hi, unsigned short* __restrict__ h_lo,
                            int* __restrict__ bar) {
    int idx = blockIdx.x * blockDim.x + threadIdx.x;
    int stride = gridDim.x * blockDim.x;
    if (idx == 0) __hip_atomic_store(bar, 0, __ATOMIC_RELAXED, __HIP_MEMORY_SCOPE_AGENT);
    for (int i = idx; i < G4 * IDIM; i += stride) {
        int np = i / IDIM, k = i - np * IDIM;
        int orig = (np & 3) * HDIM + (np >> 2);
        float f = W_ih[(size_t)orig * IDIM + k];
        unsigned short hi = f2bf(f);
        wih_hi[i] = hi;
        wih_lo[i] = f2bf(f - bf2f(hi));
    }
    for (int i = idx; i < G4 * HDIM; i += stride) {
        int np = i / HDIM, k = i - np * HDIM;
        int orig = (np & 3) * HDIM + (np >> 2);
        float f = W_hh[(size_t)orig * HDIM + k];
        unsigned short hi = f2bf(f);
        whh_hi[i] = hi;
        whh_lo[i] = f2bf(f - bf2f(hi));
    }
    for (int i = idx; i < G4; i += stride) {
        int orig = (i & 3) * HDIM + (i >> 2);
        bc[i] = b_ih[orig] + b_hh[orig];
    }
    for (int i = idx; i < BATCH * HDIM; i += stride) {
        float f = h0[i];
        unsigned short hi = f2bf(f);
        h_hi[i] = hi;                       // buffer 0
        h_lo[i] = f2bf(f - bf2f(hi));
    }
}

// ---------------------------------------------------------------------------
// xg GEMM: xg[8192][2048] = x[8192][2048] @ Wih''^T + bc   (split-3 bf16 MFMA)
// 128x128 tile, BK=64, 256 threads (4 waves, each a 64x64 quadrant).
// ---------------------------------------------------------------------------
__global__ __launch_bounds__(256) void gemm_xg(const float* __restrict__ x,
        const unsigned short* __restrict__ wih_hi, const unsigned short* __restrict__ wih_lo,
        const float* __restrict__ bc, float* __restrict__ xg) {
    __shared__ unsigned short As_hi[128][64];
    __shared__ unsigned short As_lo[128][64];
    __shared__ unsigned short Bs_hi[128][64];
    __shared__ unsigned short Bs_lo[128][64];

    int tid = threadIdx.x;
    int w = tid >> 6, l = tid & 63;
    int lr = l & 15, lc = l >> 4;
    int bid = blockIdx.x;
    int mt = bid & 63, nt = bid >> 6;       // 64 M-tiles x 16 N-tiles
    int m0 = mt * 128, n0 = nt * 128;
    int mq = (w >> 1) * 64, nq = (w & 1) * 64;

    f32x4 acc[4][4] = {};

    for (int k0 = 0; k0 < IDIM; k0 += 64) {
        // stage A: f32 -> bf16 hi/lo
        #pragma unroll
        for (int i = 0; i < 8; ++i) {
            int p = i * 256 + tid;            // 0..2047 : 128 rows x 16 chunks
            int r = p >> 4, c4 = p & 15;
            const float4 v = *(const float4*)(x + (size_t)(m0 + r) * IDIM + k0 + c4 * 4);
            unsigned short h0_ = f2bf(v.x), h1_ = f2bf(v.y), h2_ = f2bf(v.z), h3_ = f2bf(v.w);
            unsigned short l0_ = f2bf(v.x - bf2f(h0_));
            unsigned short l1_ = f2bf(v.y - bf2f(h1_));
            unsigned short l2_ = f2bf(v.z - bf2f(h2_));
            unsigned short l3_ = f2bf(v.w - bf2f(h3_));
            uint2 hw, lw;
            hw.x = (unsigned)h0_ | ((unsigned)h1_ << 16);
            hw.y = (unsigned)h2_ | ((unsigned)h3_ << 16);
            lw.x = (unsigned)l0_ | ((unsigned)l1_ << 16);
            lw.y = (unsigned)l2_ | ((unsigned)l3_ << 16);
            *(uint2*)&As_hi[r][c4 * 4] = hw;
            *(uint2*)&As_lo[r][c4 * 4] = lw;
        }
        // stage B: bf16 copy (W'' is [n'][k], k contiguous)
        #pragma unroll
        for (int i = 0; i < 4; ++i) {
            int q = i * 256 + tid;            // 0..1023 : 128 rows x 8 chunks
            int n = q >> 3, c16 = q & 7;
            size_t goff = (size_t)(n0 + n) * IDIM + k0 + c16 * 8;
            *(uint4*)&Bs_hi[n][c16 * 8] = *(const uint4*)(wih_hi + goff);
            *(uint4*)&Bs_lo[n][c16 * 8] = *(const uint4*)(wih_lo + goff);
        }
        __syncthreads();

        #pragma unroll
        for (int ks = 0; ks < 2; ++ks) {
            bf16x8 ah[4], al[4], bh[4], bl[4];
            int col = ks * 32 + lc * 8;
            #pragma unroll
            for (int mb = 0; mb < 4; ++mb) {
                int row = mq + mb * 16 + lr;
                ah[mb] = *(const bf16x8*)&As_hi[row][col];
                al[mb] = *(const bf16x8*)&As_lo[row][col];
            }
            #pragma unroll
            for (int nb = 0; nb < 4; ++nb) {
                int row = nq + nb * 16 + lr;
                bh[nb] = *(const bf16x8*)&Bs_hi[row][col];
                bl[nb] = *(const bf16x8*)&Bs_lo[row][col];
            }
            #pragma unroll
            for (int mb = 0; mb < 4; ++mb)
                #pragma unroll
                for (int nb = 0; nb < 4; ++nb) {
                    acc[mb][nb] = __builtin_amdgcn_mfma_f32_16x16x32_bf16(ah[mb], bh[nb], acc[mb][nb], 0, 0, 0);
                    acc[mb][nb] = __builtin_amdgcn_mfma_f32_16x16x32_bf16(ah[mb], bl[nb], acc[mb][nb], 0, 0, 0);
                    acc[mb][nb] = __builtin_amdgcn_mfma_f32_16x16x32_bf16(al[mb], bh[nb], acc[mb][nb], 0, 0, 0);
                }
        }
        __syncthreads();
    }

    // epilogue: + bias, store f32
    #pragma unroll
    for (int mb = 0; mb < 4; ++mb) {
        #pragma unroll
        for (int nb = 0; nb < 4; ++nb) {
            int col = n0 + nq + nb * 16 + lr;
            float bias = bc[col];
            #pragma unroll
            for (int r = 0; r < 4; ++r) {
                int row = m0 + mq + mb * 16 + lc * 4 + r;
                xg[(size_t)row * G4 + col] = acc[mb][nb][r] + bias;
            }
        }
    }
}

// ---------------------------------------------------------------------------
// Recurrence: 64 WGs x 256 thr, cooperative (co-residency only; custom
// barrier instead of cg::grid.sync). WG g owns gate cols [g*32,g*32+32) =
// hidden units j in [g*8,g*8+8). Wave w owns K-quarter [w*128,(w+1)*128).
// Whh'' fragments live in registers for all 128 steps. h double-buffered in
// global as bf16 hi/lo. One LSTM cell per thread (x2), c & sum(h) in regs.
//
// Barrier protocol per step:
//   __syncthreads()            -> each wave drains its h stores (vmcnt0)
//   thread0: fetch_add RELEASE -> buffer_wbl2 sc1 (L2 -> IC) then bump
//   thread0: spin RELAXED      -> IC-coherent polls until all 64 arrived
//   thread0: load ACQUIRE      -> invalidate L1/L2 so h reads see IC data
//   __syncthreads()            -> all waves ordered after the invalidate
// ---------------------------------------------------------------------------
__global__ __launch_bounds__(256) void lstm_rec(
        const unsigned short* __restrict__ whh_hi, const unsigned short* __restrict__ whh_lo,
        const float* __restrict__ xg, const float* __restrict__ c0,
        const float* __restrict__ mask_h, const float* __restrict__ mask_c,
        unsigned short* __restrict__ h_hi, unsigned short* __restrict__ h_lo,
        float* __restrict__ h_mean,
        const float* __restrict__ W_out, const float* __restrict__ b_out,
        float* __restrict__ out, int* __restrict__ bar) {
    __shared__ float red[4][64][32];        // 32 KB: per-wave K-partials

    int g = blockIdx.x, tid = threadIdx.x;
    int w = tid >> 6, l = tid & 63;
    int lr = l & 15, lc = l >> 4;

    // B fragments (Whh'' slice), resident in registers for the whole loop
    bf16x8 bh[2][4], bl[2][4];
    #pragma unroll
    for (int nb = 0; nb < 2; ++nb)
        #pragma unroll
        for (int ks = 0; ks < 4; ++ks) {
            int n = g * 32 + nb * 16 + lr;
            int k = w * 128 + ks * 32 + lc * 8;
            bh[nb][ks] = *(const bf16x8*)(whh_hi + (size_t)n * HDIM + k);
            bl[nb][ks] = *(const bf16x8*)(whh_lo + (size_t)n * HDIM + k);
        }

    // two cells per thread
    int b0_ = tid >> 3, jl0 = tid & 7, jg0 = g * 8 + jl0;
    int b1_ = (tid + 256) >> 3, jl1 = tid & 7, jg1 = g * 8 + jl1;
    float c_0 = c0[b0_ * HDIM + jg0];
    float c_1 = c0[b1_ * HDIM + jg1];
    float ha0 = 0.f, ha1 = 0.f;

    for (int t = 0; t < T_STEPS; ++t) {
        int cur = (t & 1) * (BATCH * HDIM);
        int nxt = ((t + 1) & 1) * (BATCH * HDIM);

        // prefetch h-independent operands (hide HBM latency under MFMA+barrier)
        const float4 xgv0 = *(const float4*)(xg + (size_t)(t * BATCH + b0_) * G4 + g * 32 + jl0 * 4);
        const float4 xgv1 = *(const float4*)(xg + (size_t)(t * BATCH + b1_) * G4 + g * 32 + jl1 * 4);
        size_t mi0 = (size_t)(t * BATCH + b0_) * HDIM + jg0;
        size_t mi1 = (size_t)(t * BATCH + b1_) * HDIM + jg1;
        float mh0 = mask_h[mi0], mc0 = mask_c[mi0];
        float mh1 = mask_h[mi1], mc1 = mask_c[mi1];

        f32x4 acc[4][2] = {};
        #pragma unroll
        for (int ks = 0; ks < 4; ++ks) {
            int k = w * 128 + ks * 32 + lc * 8;
            #pragma unroll
            for (int mb = 0; mb < 4; ++mb) {
                int row = mb * 16 + lr;
                bf16x8 ah = *(const bf16x8*)(h_hi + cur + row * HDIM + k);
                bf16x8 al = *(const bf16x8*)(h_lo + cur + row * HDIM + k);
                #pragma unroll
                for (int nb = 0; nb < 2; ++nb) {
                    acc[mb][nb] = __builtin_amdgcn_mfma_f32_16x16x32_bf16(ah, bh[nb][ks], acc[mb][nb], 0, 0, 0);
                    acc[mb][nb] = __builtin_amdgcn_mfma_f32_16x16x32_bf16(ah, bl[nb][ks], acc[mb][nb], 0, 0, 0);
                    acc[mb][nb] = __builtin_amdgcn_mfma_f32_16x16x32_bf16(al, bh[nb][ks], acc[mb][nb], 0, 0, 0);
                }
            }
        }
        #pragma unroll
        for (int mb = 0; mb < 4; ++mb)
            #pragma unroll
            for (int nb = 0; nb < 2; ++nb)
                #pragma unroll
                for (int r = 0; r < 4; ++r)
                    red[w][mb * 16 + lc * 4 + r][nb * 16 + lr] = acc[mb][nb][r];
        __syncthreads();

        // cell phase: 2 cells per thread
        #pragma unroll
        for (int e = 0; e < 2; ++e) {
            int b  = e ? b1_ : b0_;
            int jl = e ? jl1 : jl0;
            int jg = e ? jg1 : jg0;
            float c_reg = e ? c_1 : c_0;
            int nb4 = jl * 4;
            float gi = red[0][b][nb4 + 0] + red[1][b][nb4 + 0] + red[2][b][nb4 + 0] + red[3][b][nb4 + 0];
            float gf = red[0][b][nb4 + 1] + red[1][b][nb4 + 1] + red[2][b][nb4 + 1] + red[3][b][nb4 + 1];
            float gg = red[0][b][nb4 + 2] + red[1][b][nb4 + 2] + red[2][b][nb4 + 2] + red[3][b][nb4 + 2];
            float go = red[0][b][nb4 + 3] + red[1][b][nb4 + 3] + red[2][b][nb4 + 3] + red[3][b][nb4 + 3];
            const float4 xgv = e ? xgv1 : xgv0;
            gi += xgv.x; gf += xgv.y; gg += xgv.z; go += xgv.w;
            float i_s = 1.f / (1.f + expf(-gi));
            float f_s = 1.f / (1.f + expf(-gf));
            float o_s = 1.f / (1.f + expf(-go));
            float c_new = f_s * c_reg + i_s * tanhf(gg);
            float h_new = o_s * tanhf(c_new);
            h_new *= (e ? mh1 : mh0);
            c_new *= (e ? mc1 : mc0);
            if (e) { c_1 = c_new; ha1 += h_new; } else { c_0 = c_new; ha0 += h_new; }
            unsigned short hh = f2bf(h_new);
            unsigned short hl = f2bf(h_new - bf2f(hh));
            h_hi[nxt + b * HDIM + jg] = hh;
            h_lo[nxt + b * HDIM + jg] = hl;
        }

        // custom grid barrier
        __syncthreads();                          // drains h stores (vmcnt0 before s_barrier)
        if (tid == 0) {
            __hip_atomic_fetch_add(bar, 1, __ATOMIC_RELEASE, __HIP_MEMORY_SCOPE_AGENT);
            int target = 64 * (t + 1);
            while (__hip_atomic_load(bar, __ATOMIC_RELAXED, __HIP_MEMORY_SCOPE_AGENT) < target)
                __builtin_amdgcn_s_sleep(1);
            int v = __hip_atomic_load(bar, __ATOMIC_ACQUIRE, __HIP_MEMORY_SCOPE_AGENT);
            asm volatile("" :: "v"(v));           // keep the acquire live
        }
        __syncthreads();
    }

    h_mean[b0_ * HDIM + jg0] = ha0 * (1.f / T_STEPS);
    h_mean[b1_ * HDIM + jg1] = ha1 * (1.f / T_STEPS);

    // final barrier before the projection
    __syncthreads();
    if (tid == 0) {
        __hip_atomic_fetch_add(bar, 1, __ATOMIC_RELEASE, __HIP_MEMORY_SCOPE_AGENT);
        int target = 64 * (T_STEPS + 1);
        while (__hip_atomic_load(bar, __ATOMIC_RELAXED, __HIP_MEMORY_SCOPE_AGENT) < target)
            __builtin_amdgcn_s_sleep(1);
        int v = __hip_atomic_load(bar, __ATOMIC_ACQUIRE, __HIP_MEMORY_SCOPE_AGENT);
        asm volatile("" :: "v"(v));
    }
    __syncthreads();

    // projection: WG g handles batch b = g -> out[g*11 + cl]
    {
        float part[NCLS];
        #pragma unroll
        for (int cl = 0; cl < NCLS; ++cl) part[cl] = 0.f;
        for (int j = tid; j < HDIM; j += 256) {
            float hv = h_mean[g * HDIM + j];
            #pragma unroll
            for (int cl = 0; cl < NCLS; ++cl)
                part[cl] += hv * W_out[cl * HDIM + j];
        }
        float* rbuf = (float*)red;                // 8192 floats, need 11*256
        #pragma unroll
        for (int cl = 0; cl < NCLS; ++cl) rbuf[cl * 256 + tid] = part[cl];
        __syncthreads();
        if (tid < NCLS) {
            float s = b_out[tid];
            for (int i = 0; i < 256; ++i) s += rbuf[tid * 256 + i];
            out[g * NCLS + tid] = s;
        }
    }
}

// ---------------------------------------------------------------------------
extern "C" void kernel_launch(void* const* d_in, const int* in_sizes, int n_in,
                              void* d_out, int out_size, void* d_ws, size_t ws_size,
                              hipStream_t stream) {
    const float* x      = (const float*)d_in[0];
    const float* h0     = (const float*)d_in[1];
    const float* c0     = (const float*)d_in[2];
    const float* W_ih   = (const float*)d_in[3];
    const float* W_hh   = (const float*)d_in[4];
    const float* b_ih   = (const float*)d_in[5];
    const float* b_hh   = (const float*)d_in[6];
    const float* W_out  = (const float*)d_in[7];
    const float* b_out  = (const float*)d_in[8];
    const float* mask_h = (const float*)d_in[9];
    const float* mask_c = (const float*)d_in[10];
    float* out = (float*)d_out;

    char* ws = (char*)d_ws;
    float*          xg     = (float*)(ws + 0);               // 67,108,864 B
    unsigned short* wih_hi = (unsigned short*)(ws + 67108864);   // 8,388,608
    unsigned short* wih_lo = (unsigned short*)(ws + 75497472);   // 8,388,608
    unsigned short* whh_hi = (unsigned short*)(ws + 83886080);   // 2,097,152
    unsigned short* whh_lo = (unsigned short*)(ws + 85983232);   // 2,097,152
    float*          bc     = (float*)(ws + 88080384);            // 8,192
    unsigned short* h_hi   = (unsigned short*)(ws + 88088576);   // 131,072 (2 bufs)
    unsigned short* h_lo   = (unsigned short*)(ws + 88219648);   // 131,072
    float*          h_mean = (float*)(ws + 88350720);            // 131,072
    int*            bar    = (int*)(ws + 88481792);              // 4

    prep_kernel<<<8192, 256, 0, stream>>>(W_ih, W_hh, b_ih, b_hh, h0,
                                          wih_hi, wih_lo, whh_hi, whh_lo, bc, h_hi, h_lo, bar);
    gemm_xg<<<1024, 256, 0, stream>>>(x, wih_hi, wih_lo, bc, xg);

    void* args[] = { &whh_hi, &whh_lo, &xg, &c0, &mask_h, &mask_c,
                     &h_hi, &h_lo, &h_mean, &W_out, &b_out, &out, &bar };
    hipLaunchCooperativeKernel((void*)lstm_rec, dim3(64), dim3(256), args, 0, stream);
}

// Round 3
// 1601.231 us; speedup vs baseline: 1.5782x; 1.0420x over previous
//
#include <hip/hip_runtime.h>
#include <cstdint>

#define T_STEPS 128
#define BATCH 64
#define IDIM 2048
#define HDIM 512
#define G4 2048   // 4*H
#define NCLS 11

typedef __attribute__((ext_vector_type(8))) short bf16x8;
typedef __attribute__((ext_vector_type(4))) float f32x4;

__device__ __forceinline__ unsigned short f2bf(float f) {
    unsigned int u = __builtin_bit_cast(unsigned int, f);
    unsigned int r = u + 0x7FFFu + ((u >> 16) & 1u);   // RNE
    return (unsigned short)(r >> 16);
}
__device__ __forceinline__ float bf2f(unsigned short b) {
    unsigned int u = ((unsigned int)b) << 16;
    return __builtin_bit_cast(float, u);
}

#define FLAG_STRIDE 32   // ints: 128 B per WG flag line

// ---------------------------------------------------------------------------
// Prep: permute gate rows to interleaved order (n' = 4*j + gate), split
// weights into bf16 hi/lo, combine biases, split h0 into h buffer 0.
// orig_row(n') = (n'&3)*512 + (n'>>2).  Also zero the barrier flag array.
// ---------------------------------------------------------------------------
__global__ void prep_kernel(const float* __restrict__ W_ih, const float* __restrict__ W_hh,
                            const float* __restrict__ b_ih, const float* __restrict__ b_hh,
                            const float* __restrict__ h0,
                            unsigned short* __restrict__ wih_hi, unsigned short* __restrict__ wih_lo,
                            unsigned short* __restrict__ whh_hi, unsigned short* __restrict__ whh_lo,
                            float* __restrict__ bc,
                            unsigned short* __restrict__ h_hi, unsigned short* __restrict__ h_lo,
                            int* __restrict__ flags) {
    int idx = blockIdx.x * blockDim.x + threadIdx.x;
    int stride = gridDim.x * blockDim.x;
    for (int i = idx; i < 64 * FLAG_STRIDE; i += stride)
        __hip_atomic_store(flags + i, 0, __ATOMIC_RELAXED, __HIP_MEMORY_SCOPE_AGENT);
    for (int i = idx; i < G4 * IDIM; i += stride) {
        int np = i / IDIM, k = i - np * IDIM;
        int orig = (np & 3) * HDIM + (np >> 2);
        float f = W_ih[(size_t)orig * IDIM + k];
        unsigned short hi = f2bf(f);
        wih_hi[i] = hi;
        wih_lo[i] = f2bf(f - bf2f(hi));
    }
    for (int i = idx; i < G4 * HDIM; i += stride) {
        int np = i / HDIM, k = i - np * HDIM;
        int orig = (np & 3) * HDIM + (np >> 2);
        float f = W_hh[(size_t)orig * HDIM + k];
        unsigned short hi = f2bf(f);
        whh_hi[i] = hi;
        whh_lo[i] = f2bf(f - bf2f(hi));
    }
    for (int i = idx; i < G4; i += stride) {
        int orig = (i & 3) * HDIM + (i >> 2);
        bc[i] = b_ih[orig] + b_hh[orig];
    }
    for (int i = idx; i < BATCH * HDIM; i += stride) {
        float f = h0[i];
        unsigned short hi = f2bf(f);
        h_hi[i] = hi;                       // buffer 0
        h_lo[i] = f2bf(f - bf2f(hi));
    }
}

// ---------------------------------------------------------------------------
// xg GEMM: xg[8192][2048] = x[8192][2048] @ Wih''^T + bc   (split-3 bf16 MFMA)
// 128x128 tile, BK=64, 256 threads (4 waves, each a 64x64 quadrant).
// ---------------------------------------------------------------------------
__global__ __launch_bounds__(256) void gemm_xg(const float* __restrict__ x,
        const unsigned short* __restrict__ wih_hi, const unsigned short* __restrict__ wih_lo,
        const float* __restrict__ bc, float* __restrict__ xg) {
    __shared__ unsigned short As_hi[128][64];
    __shared__ unsigned short As_lo[128][64];
    __shared__ unsigned short Bs_hi[128][64];
    __shared__ unsigned short Bs_lo[128][64];

    int tid = threadIdx.x;
    int w = tid >> 6, l = tid & 63;
    int lr = l & 15, lc = l >> 4;
    int bid = blockIdx.x;
    int mt = bid & 63, nt = bid >> 6;       // 64 M-tiles x 16 N-tiles
    int m0 = mt * 128, n0 = nt * 128;
    int mq = (w >> 1) * 64, nq = (w & 1) * 64;

    f32x4 acc[4][4] = {};

    for (int k0 = 0; k0 < IDIM; k0 += 64) {
        // stage A: f32 -> bf16 hi/lo
        #pragma unroll
        for (int i = 0; i < 8; ++i) {
            int p = i * 256 + tid;            // 0..2047 : 128 rows x 16 chunks
            int r = p >> 4, c4 = p & 15;
            const float4 v = *(const float4*)(x + (size_t)(m0 + r) * IDIM + k0 + c4 * 4);
            unsigned short h0_ = f2bf(v.x), h1_ = f2bf(v.y), h2_ = f2bf(v.z), h3_ = f2bf(v.w);
            unsigned short l0_ = f2bf(v.x - bf2f(h0_));
            unsigned short l1_ = f2bf(v.y - bf2f(h1_));
            unsigned short l2_ = f2bf(v.z - bf2f(h2_));
            unsigned short l3_ = f2bf(v.w - bf2f(h3_));
            uint2 hw, lw;
            hw.x = (unsigned)h0_ | ((unsigned)h1_ << 16);
            hw.y = (unsigned)h2_ | ((unsigned)h3_ << 16);
            lw.x = (unsigned)l0_ | ((unsigned)l1_ << 16);
            lw.y = (unsigned)l2_ | ((unsigned)l3_ << 16);
            *(uint2*)&As_hi[r][c4 * 4] = hw;
            *(uint2*)&As_lo[r][c4 * 4] = lw;
        }
        // stage B: bf16 copy (W'' is [n'][k], k contiguous)
        #pragma unroll
        for (int i = 0; i < 4; ++i) {
            int q = i * 256 + tid;            // 0..1023 : 128 rows x 8 chunks
            int n = q >> 3, c16 = q & 7;
            size_t goff = (size_t)(n0 + n) * IDIM + k0 + c16 * 8;
            *(uint4*)&Bs_hi[n][c16 * 8] = *(const uint4*)(wih_hi + goff);
            *(uint4*)&Bs_lo[n][c16 * 8] = *(const uint4*)(wih_lo + goff);
        }
        __syncthreads();

        #pragma unroll
        for (int ks = 0; ks < 2; ++ks) {
            bf16x8 ah[4], al[4], bh[4], bl[4];
            int col = ks * 32 + lc * 8;
            #pragma unroll
            for (int mb = 0; mb < 4; ++mb) {
                int row = mq + mb * 16 + lr;
                ah[mb] = *(const bf16x8*)&As_hi[row][col];
                al[mb] = *(const bf16x8*)&As_lo[row][col];
            }
            #pragma unroll
            for (int nb = 0; nb < 4; ++nb) {
                int row = nq + nb * 16 + lr;
                bh[nb] = *(const bf16x8*)&Bs_hi[row][col];
                bl[nb] = *(const bf16x8*)&Bs_lo[row][col];
            }
            #pragma unroll
            for (int mb = 0; mb < 4; ++mb)
                #pragma unroll
                for (int nb = 0; nb < 4; ++nb) {
                    acc[mb][nb] = __builtin_amdgcn_mfma_f32_16x16x32_bf16(ah[mb], bh[nb], acc[mb][nb], 0, 0, 0);
                    acc[mb][nb] = __builtin_amdgcn_mfma_f32_16x16x32_bf16(ah[mb], bl[nb], acc[mb][nb], 0, 0, 0);
                    acc[mb][nb] = __builtin_amdgcn_mfma_f32_16x16x32_bf16(al[mb], bh[nb], acc[mb][nb], 0, 0, 0);
                }
        }
        __syncthreads();
    }

    // epilogue: + bias, store f32
    #pragma unroll
    for (int mb = 0; mb < 4; ++mb) {
        #pragma unroll
        for (int nb = 0; nb < 4; ++nb) {
            int col = n0 + nq + nb * 16 + lr;
            float bias = bc[col];
            #pragma unroll
            for (int r = 0; r < 4; ++r) {
                int row = m0 + mq + mb * 16 + lc * 4 + r;
                xg[(size_t)row * G4 + col] = acc[mb][nb][r] + bias;
            }
        }
    }
}

// ---------------------------------------------------------------------------
// Distributed grid barrier: per-WG flag line (128 B apart), RELEASE store,
// 64 lanes of wave 0 poll all 64 flags in parallel, ACQUIRE to invalidate.
// Flags are monotonic within a launch (t+1), zeroed by prep each launch.
// ---------------------------------------------------------------------------
__device__ __forceinline__ void grid_barrier(int* __restrict__ flags, int g, int tid, int target) {
    __syncthreads();                          // drains h stores (vmcnt0 before s_barrier)
    if (tid == 0)
        __hip_atomic_store(flags + g * FLAG_STRIDE, target, __ATOMIC_RELEASE, __HIP_MEMORY_SCOPE_AGENT);
    if (tid < 64) {
        while (__hip_atomic_load(flags + tid * FLAG_STRIDE, __ATOMIC_RELAXED, __HIP_MEMORY_SCOPE_AGENT) < target)
            __builtin_amdgcn_s_sleep(1);
    }
    if (tid == 0) {
        int v = __hip_atomic_load(flags + g * FLAG_STRIDE, __ATOMIC_ACQUIRE, __HIP_MEMORY_SCOPE_AGENT);
        asm volatile("" :: "v"(v));           // keep the acquire live
    }
    __syncthreads();
}

// ---------------------------------------------------------------------------
// Recurrence: 64 WGs x 256 thr, cooperative (co-residency only; custom
// barrier). WG g owns gate cols [g*32,g*32+32) = hidden units j in
// [g*8,g*8+8). Wave w owns K-quarter [w*128,(w+1)*128). Whh'' fragments live
// in registers for all 128 steps. h double-buffered in global as bf16 hi/lo.
// Two LSTM cells per thread; c & sum(h) in regs.
// ---------------------------------------------------------------------------
__global__ __launch_bounds__(256) void lstm_rec(
        const unsigned short* __restrict__ whh_hi, const unsigned short* __restrict__ whh_lo,
        const float* __restrict__ xg, const float* __restrict__ c0,
        const float* __restrict__ mask_h, const float* __restrict__ mask_c,
        unsigned short* __restrict__ h_hi, unsigned short* __restrict__ h_lo,
        float* __restrict__ h_mean,
        const float* __restrict__ W_out, const float* __restrict__ b_out,
        float* __restrict__ out, int* __restrict__ flags) {
    __shared__ float red[4][64][32];        // 32 KB: per-wave K-partials

    int g = blockIdx.x, tid = threadIdx.x;
    int w = tid >> 6, l = tid & 63;
    int lr = l & 15, lc = l >> 4;

    // B fragments (Whh'' slice), resident in registers for the whole loop
    bf16x8 bh[2][4], bl[2][4];
    #pragma unroll
    for (int nb = 0; nb < 2; ++nb)
        #pragma unroll
        for (int ks = 0; ks < 4; ++ks) {
            int n = g * 32 + nb * 16 + lr;
            int k = w * 128 + ks * 32 + lc * 8;
            bh[nb][ks] = *(const bf16x8*)(whh_hi + (size_t)n * HDIM + k);
            bl[nb][ks] = *(const bf16x8*)(whh_lo + (size_t)n * HDIM + k);
        }

    // two cells per thread
    int b0_ = tid >> 3, jl0 = tid & 7, jg0 = g * 8 + jl0;
    int b1_ = (tid + 256) >> 3, jl1 = tid & 7, jg1 = g * 8 + jl1;
    float c_0 = c0[b0_ * HDIM + jg0];
    float c_1 = c0[b1_ * HDIM + jg1];
    float ha0 = 0.f, ha1 = 0.f;

    for (int t = 0; t < T_STEPS; ++t) {
        int cur = (t & 1) * (BATCH * HDIM);
        int nxt = ((t + 1) & 1) * (BATCH * HDIM);

        // prefetch h-independent operands (hide HBM latency under MFMA)
        const float4 xgv0 = *(const float4*)(xg + (size_t)(t * BATCH + b0_) * G4 + g * 32 + jl0 * 4);
        const float4 xgv1 = *(const float4*)(xg + (size_t)(t * BATCH + b1_) * G4 + g * 32 + jl1 * 4);
        size_t mi0 = (size_t)(t * BATCH + b0_) * HDIM + jg0;
        size_t mi1 = (size_t)(t * BATCH + b1_) * HDIM + jg1;
        float mh0 = mask_h[mi0], mc0 = mask_c[mi0];
        float mh1 = mask_h[mi1], mc1 = mask_c[mi1];

        f32x4 acc[4][2] = {};
        #pragma unroll
        for (int ks = 0; ks < 4; ++ks) {
            int k = w * 128 + ks * 32 + lc * 8;
            #pragma unroll
            for (int mb = 0; mb < 4; ++mb) {
                int row = mb * 16 + lr;
                bf16x8 ah = *(const bf16x8*)(h_hi + cur + row * HDIM + k);
                bf16x8 al = *(const bf16x8*)(h_lo + cur + row * HDIM + k);
                #pragma unroll
                for (int nb = 0; nb < 2; ++nb) {
                    acc[mb][nb] = __builtin_amdgcn_mfma_f32_16x16x32_bf16(ah, bh[nb][ks], acc[mb][nb], 0, 0, 0);
                    acc[mb][nb] = __builtin_amdgcn_mfma_f32_16x16x32_bf16(ah, bl[nb][ks], acc[mb][nb], 0, 0, 0);
                    acc[mb][nb] = __builtin_amdgcn_mfma_f32_16x16x32_bf16(al, bh[nb][ks], acc[mb][nb], 0, 0, 0);
                }
            }
        }
        #pragma unroll
        for (int mb = 0; mb < 4; ++mb)
            #pragma unroll
            for (int nb = 0; nb < 2; ++nb)
                #pragma unroll
                for (int r = 0; r < 4; ++r)
                    red[w][mb * 16 + lc * 4 + r][nb * 16 + lr] = acc[mb][nb][r];
        __syncthreads();

        // cell phase: 2 cells per thread
        #pragma unroll
        for (int e = 0; e < 2; ++e) {
            int b  = e ? b1_ : b0_;
            int jl = e ? jl1 : jl0;
            int jg = e ? jg1 : jg0;
            float c_reg = e ? c_1 : c_0;
            int nb4 = jl * 4;
            float gi = red[0][b][nb4 + 0] + red[1][b][nb4 + 0] + red[2][b][nb4 + 0] + red[3][b][nb4 + 0];
            float gf = red[0][b][nb4 + 1] + red[1][b][nb4 + 1] + red[2][b][nb4 + 1] + red[3][b][nb4 + 1];
            float gg = red[0][b][nb4 + 2] + red[1][b][nb4 + 2] + red[2][b][nb4 + 2] + red[3][b][nb4 + 2];
            float go = red[0][b][nb4 + 3] + red[1][b][nb4 + 3] + red[2][b][nb4 + 3] + red[3][b][nb4 + 3];
            const float4 xgv = e ? xgv1 : xgv0;
            gi += xgv.x; gf += xgv.y; gg += xgv.z; go += xgv.w;
            float i_s = 1.f / (1.f + expf(-gi));
            float f_s = 1.f / (1.f + expf(-gf));
            float o_s = 1.f / (1.f + expf(-go));
            float c_new = f_s * c_reg + i_s * tanhf(gg);
            float h_new = o_s * tanhf(c_new);
            h_new *= (e ? mh1 : mh0);
            c_new *= (e ? mc1 : mc0);
            if (e) { c_1 = c_new; ha1 += h_new; } else { c_0 = c_new; ha0 += h_new; }
            unsigned short hh = f2bf(h_new);
            unsigned short hl = f2bf(h_new - bf2f(hh));
            h_hi[nxt + b * HDIM + jg] = hh;
            h_lo[nxt + b * HDIM + jg] = hl;
        }

        grid_barrier(flags, g, tid, t + 1);
    }

    h_mean[b0_ * HDIM + jg0] = ha0 * (1.f / T_STEPS);
    h_mean[b1_ * HDIM + jg1] = ha1 * (1.f / T_STEPS);

    grid_barrier(flags, g, tid, T_STEPS + 1);

    // projection: WG g handles batch b = g -> out[g*11 + cl]
    {
        float part[NCLS];
        #pragma unroll
        for (int cl = 0; cl < NCLS; ++cl) part[cl] = 0.f;
        for (int j = tid; j < HDIM; j += 256) {
            float hv = h_mean[g * HDIM + j];
            #pragma unroll
            for (int cl = 0; cl < NCLS; ++cl)
                part[cl] += hv * W_out[cl * HDIM + j];
        }
        float* rbuf = (float*)red;                // 8192 floats, need 11*256
        #pragma unroll
        for (int cl = 0; cl < NCLS; ++cl) rbuf[cl * 256 + tid] = part[cl];
        __syncthreads();
        if (tid < NCLS) {
            float s = b_out[tid];
            for (int i = 0; i < 256; ++i) s += rbuf[tid * 256 + i];
            out[g * NCLS + tid] = s;
        }
    }
}

// ---------------------------------------------------------------------------
extern "C" void kernel_launch(void* const* d_in, const int* in_sizes, int n_in,
                              void* d_out, int out_size, void* d_ws, size_t ws_size,
                              hipStream_t stream) {
    const float* x      = (const float*)d_in[0];
    const float* h0     = (const float*)d_in[1];
    const float* c0     = (const float*)d_in[2];
    const float* W_ih   = (const float*)d_in[3];
    const float* W_hh   = (const float*)d_in[4];
    const float* b_ih   = (const float*)d_in[5];
    const float* b_hh   = (const float*)d_in[6];
    const float* W_out  = (const float*)d_in[7];
    const float* b_out  = (const float*)d_in[8];
    const float* mask_h = (const float*)d_in[9];
    const float* mask_c = (const float*)d_in[10];
    float* out = (float*)d_out;

    char* ws = (char*)d_ws;
    float*          xg     = (float*)(ws + 0);               // 67,108,864 B
    unsigned short* wih_hi = (unsigned short*)(ws + 67108864);   // 8,388,608
    unsigned short* wih_lo = (unsigned short*)(ws + 75497472);   // 8,388,608
    unsigned short* whh_hi = (unsigned short*)(ws + 83886080);   // 2,097,152
    unsigned short* whh_lo = (unsigned short*)(ws + 85983232);   // 2,097,152
    float*          bc     = (float*)(ws + 88080384);            // 8,192
    unsigned short* h_hi   = (unsigned short*)(ws + 88088576);   // 131,072 (2 bufs)
    unsigned short* h_lo   = (unsigned short*)(ws + 88219648);   // 131,072
    float*          h_mean = (float*)(ws + 88350720);            // 131,072
    int*            flags  = (int*)(ws + 88481792);              // 8,192

    prep_kernel<<<8192, 256, 0, stream>>>(W_ih, W_hh, b_ih, b_hh, h0,
                                          wih_hi, wih_lo, whh_hi, whh_lo, bc, h_hi, h_lo, flags);
    gemm_xg<<<1024, 256, 0, stream>>>(x, wih_hi, wih_lo, bc, xg);

    void* args[] = { &whh_hi, &whh_lo, &xg, &c0, &mask_h, &mask_c,
                     &h_hi, &h_lo, &h_mean, &W_out, &b_out, &out, &flags };
    hipLaunchCooperativeKernel((void*)lstm_rec, dim3(64), dim3(256), args, 0, stream);
}